// Round 7
// baseline (227.545 us; speedup 1.0000x reference)
//
#include <hip/hip_runtime.h>
#include <cstdint>
#include <cstddef>

// CrossMultiheadAttention: B=2, S=2048, E=1024, NHEAD=16, HEAD=64
// cast fp32->bf16 (fused) -> MFMA QKV projection (Q pre-scaled by 0.125*log2e,
// V projection computes C^T so V^T stores coalesce) -> flash attention on
// mfma_f32_32x32x16_bf16 with sigma-permuted K staging (P^T packs in-lane, no
// shuffles), max-free softmax (raw v_exp_f32, bounded scores), KV-split-N
// (N=4 if ws permits, else 2) -> combine kernel normalizes.

using bf16 = __bf16;
typedef __bf16 bf16x8 __attribute__((ext_vector_type(8)));
typedef float f32x4 __attribute__((ext_vector_type(4)));
typedef float f32x16 __attribute__((ext_vector_type(16)));
using uint32 = unsigned int;

__device__ __forceinline__ void async16(void* lds, const void* g) {
  __builtin_amdgcn_global_load_lds((__attribute__((address_space(1))) void*)g,
                                   (__attribute__((address_space(3))) void*)lds,
                                   16, 0, 0);
}

__device__ __forceinline__ uint32 pack_bf16x2(float lo, float hi_) {
  union { bf16 h[2]; uint32 u; } w;
  w.h[0] = (bf16)lo; w.h[1] = (bf16)hi_;
  return w.u;
}

// ---------------------------------------------------------------- fused cast
// segments (float4 units): emb 1048576 | q 1048576 | wk 262144 | wq | wv
__global__ void cast_all_kernel(const float* __restrict__ e, const float* __restrict__ q,
                                const float* __restrict__ wk, const float* __restrict__ wq,
                                const float* __restrict__ wv, bf16* __restrict__ dst) {
  int i = blockIdx.x * blockDim.x + threadIdx.x;
  if (i >= 2883584) return;
  const float* src; int off;
  if (i < 1048576)      { src = e;  off = 0; }
  else if (i < 2097152) { src = q;  off = 1048576; }
  else if (i < 2359296) { src = wk; off = 2097152; }
  else if (i < 2621440) { src = wq; off = 2359296; }
  else                  { src = wv; off = 2621440; }
  float4 v = reinterpret_cast<const float4*>(src)[i - off];
  union { bf16 h[4]; unsigned long long u; } o;
  o.h[0] = (bf16)v.x; o.h[1] = (bf16)v.y; o.h[2] = (bf16)v.z; o.h[3] = (bf16)v.w;
  reinterpret_cast<unsigned long long*>(dst)[i] = o.u;
}

// ---------------------------------------------------------------- projection
// C[4096,1024] = A[4096,1024] @ W[1024,1024]^T (+bias). 128x128 tile, BK=64.
// proj 0: K -> Kp[b,h,s,64]; proj 1: Q*(0.125*log2e) -> Qp[b,h,s,64]
// proj 2: computes C^T (swapped MFMA operands) -> Vt[b,h,64,s], coalesced.
__global__ __launch_bounds__(256) void proj_kernel(
    const bf16* __restrict__ emb, const bf16* __restrict__ qin,
    const bf16* __restrict__ wk, const bf16* __restrict__ wq, const bf16* __restrict__ wv,
    const float* __restrict__ bk, const float* __restrict__ bq, const float* __restrict__ bv,
    bf16* __restrict__ Kp, bf16* __restrict__ Qp, bf16* __restrict__ Vt)
{
  __shared__ bf16 As[128 * 64];
  __shared__ bf16 Bs[128 * 64];

  int pid = blockIdx.x;
  int proj = pid >> 8;
  int t = pid & 255;
  int m0 = (t >> 3) * 128;
  int n0 = (t & 7) * 128;

  const bf16* A = (proj == 1) ? qin : emb;
  const bf16* W = (proj == 0) ? wk : (proj == 1) ? wq : wv;
  const float* bias = (proj == 0) ? bk : (proj == 1) ? bq : bv;
  const bool proj2 = (proj == 2);

  int tid = threadIdx.x;
  int lane = tid & 63, wid = tid >> 6;
  int quad = lane >> 4, l16 = lane & 15;
  int moff = (wid & 1) * 64, noff = (wid >> 1) * 64;

  f32x4 zero = {0.f, 0.f, 0.f, 0.f};
  f32x4 acc[4][4];
#pragma unroll
  for (int i = 0; i < 4; i++)
#pragma unroll
    for (int j = 0; j < 4; j++) acc[i][j] = zero;

  for (int kk = 0; kk < 1024; kk += 64) {
    __syncthreads();
#pragma unroll
    for (int i = 0; i < 4; i++) {
      int c = i * 256 + tid;
      int row = c >> 3;
      int ko = ((c ^ row) & 7) << 3;
      async16(&As[(size_t)(i * 256 + wid * 64) * 8], &A[(size_t)(m0 + row) * 1024 + kk + ko]);
      async16(&Bs[(size_t)(i * 256 + wid * 64) * 8], &W[(size_t)(n0 + row) * 1024 + kk + ko]);
    }
    __syncthreads();
#pragma unroll
    for (int ks = 0; ks < 2; ks++) {
      bf16x8 af[4], bfr[4];
#pragma unroll
      for (int i = 0; i < 4; i++) {
        int row = moff + i * 16 + l16;
        af[i] = *reinterpret_cast<const bf16x8*>(&As[row * 64 + ((((ks << 2) | quad) ^ row) & 7) * 8]);
      }
#pragma unroll
      for (int j = 0; j < 4; j++) {
        int row = noff + j * 16 + l16;
        bfr[j] = *reinterpret_cast<const bf16x8*>(&Bs[row * 64 + ((((ks << 2) | quad) ^ row) & 7) * 8]);
      }
      if (proj2) {
#pragma unroll
        for (int i = 0; i < 4; i++)
#pragma unroll
          for (int j = 0; j < 4; j++)
            acc[i][j] = __builtin_amdgcn_mfma_f32_16x16x32_bf16(bfr[j], af[i], acc[i][j], 0, 0, 0);
      } else {
#pragma unroll
        for (int i = 0; i < 4; i++)
#pragma unroll
          for (int j = 0; j < 4; j++)
            acc[i][j] = __builtin_amdgcn_mfma_f32_16x16x32_bf16(af[i], bfr[j], acc[i][j], 0, 0, 0);
      }
    }
  }

  if (proj2) {
#pragma unroll
    for (int i = 0; i < 4; i++) {
      int grow = m0 + moff + i * 16 + l16;
      int bb = grow >> 11;
      int ss = grow & 2047;
#pragma unroll
      for (int j = 0; j < 4; j++) {
#pragma unroll
        for (int r = 0; r < 4; r++) {
          int gcol = n0 + noff + j * 16 + quad * 4 + r;
          int hh = gcol >> 6, dd = gcol & 63;
          int bh = bb * 16 + hh;
          float v = acc[i][j][r] + bias[gcol];
          Vt[((size_t)bh * 64 + dd) * 2048 + ss] = (bf16)v;
        }
      }
    }
  } else {
    float bvv[4];
#pragma unroll
    for (int j = 0; j < 4; j++) bvv[j] = bias[n0 + noff + j * 16 + l16];
    bf16* dst = (proj == 0) ? Kp : Qp;
    // Q scale: 1/sqrt(64) * log2(e) so attention uses exp2 directly
    const float qs = (proj == 1) ? 0.18033688011112042f : 1.0f;
#pragma unroll
    for (int i = 0; i < 4; i++) {
#pragma unroll
      for (int r = 0; r < 4; r++) {
        int grow = m0 + moff + i * 16 + quad * 4 + r;
        int bb = grow >> 11;
        int ss = grow & 2047;
#pragma unroll
        for (int j = 0; j < 4; j++) {
          int gcol = n0 + noff + j * 16 + l16;
          int hh = gcol >> 6, dd = gcol & 63;
          int bh = bb * 16 + hh;
          float v = (acc[i][j][r] + bvv[j]) * qs;
          dst[((size_t)bh * 2048 + ss) * 64 + dd] = (bf16)v;
        }
      }
    }
  }
}

// ---------------------------------------------------------------- attention
// Grid 512<<lsplit: bid -> {half(lsplit b), qtile(4b), bh(5b)}. Block = 4 waves
// x 32 queries, processes (2048>>lsplit) keys as 64-key tiles. sigma-permuted K
// staging (swap bits 2<->3 of row within each 16) makes S^T's C-layout rows
// already B-operand-ordered for PV: P^T packs in-lane. Max-free softmax:
// p = exp2(s) via raw v_exp_f32. Writes unnormalized O^T partial (fp32) + l;
// combine kernel merges the halves.
__global__ __launch_bounds__(256, 5) void attn_kernel(
    const bf16* __restrict__ Qp, const bf16* __restrict__ Kp, const bf16* __restrict__ Vt,
    float* __restrict__ out, float* __restrict__ part, float* __restrict__ lbuf,
    int lsplit)
{
  __shared__ bf16 Ks[2][64 * 64];   // [key(sigma-permuted)][dim], chunk-swizzled
  __shared__ bf16 Vs[2][64 * 64];   // [dim][key], chunk-swizzled

  int bid = blockIdx.x;
  int nsplit = 1 << lsplit;
  int half = bid & (nsplit - 1);
  int q0 = ((bid >> lsplit) & 15) << 7;
  int bh = bid >> (4 + lsplit);
  int bb = bh >> 4, hh = bh & 15;
  int ntiles = 32 >> lsplit;        // 64-key tiles per block
  int g0 = half * ntiles;           // first 64-key tile index

  const bf16* Qg = Qp + (size_t)bh * (2048 * 64);
  const bf16* Kg = Kp + (size_t)bh * (2048 * 64);
  const bf16* Vg = Vt + (size_t)bh * (64 * 2048);

  int tid = threadIdx.x, lane = tid & 63, wid = tid >> 6;
  int l32 = lane & 31;
  int h = lane >> 5;
  int wq0 = q0 + wid * 32;

  auto stage = [&](int kt_, int buf) {   // kt_ = global 64-key tile index
#pragma unroll
    for (int i = 0; i < 2; i++) {
      int c = i * 256 + tid;
      int row = c >> 3;
      int srow = (row & ~12) | ((row & 4) << 1) | ((row & 8) >> 1);  // swap bits 2,3
      int ko = ((c ^ row) & 7) << 3;
      async16(&Ks[buf][(size_t)(i * 256 + wid * 64) * 8], &Kg[(size_t)(kt_ * 64 + srow) * 64 + ko]);
      async16(&Vs[buf][(size_t)(i * 256 + wid * 64) * 8], &Vg[(size_t)row * 2048 + kt_ * 64 + ko]);
    }
  };

  // Q^T B-operand fragments, direct from global (b128, once)
  bf16x8 qf[4];
#pragma unroll
  for (int s = 0; s < 4; s++)
    qf[s] = *reinterpret_cast<const bf16x8*>(
        &Qg[(size_t)(wq0 + l32) * 64 + s * 16 + h * 8]);

  stage(g0, 0);

  const f32x16 z16 = {0.f, 0.f, 0.f, 0.f, 0.f, 0.f, 0.f, 0.f,
                      0.f, 0.f, 0.f, 0.f, 0.f, 0.f, 0.f, 0.f};
  f32x16 Ov[2];
  Ov[0] = z16; Ov[1] = z16;
  float l_i = 0.f;

  for (int kt = 0; kt < ntiles; kt++) {
    int cur = kt & 1;
    __syncthreads();                          // staging for buf[cur] complete
    __builtin_amdgcn_sched_barrier(0);
    if (kt < ntiles - 1) stage(g0 + kt + 1, cur ^ 1);  // prefetch other buffer
    __builtin_amdgcn_sched_barrier(0);

    const bf16* Kc = Ks[cur];
    const bf16* Vc = Vs[cur];

    // S^T = K(64x64, sigma-rows) Q^T(64x32): two 32-key C tiles.
    // First MFMA consumes the loop-invariant zero vector (no per-iter init).
    f32x16 St[2];
#pragma unroll
    for (int t = 0; t < 2; t++) {
      int row = t * 32 + l32;
      {
        bf16x8 kf = *reinterpret_cast<const bf16x8*>(&Kc[row * 64 + ((h ^ row) & 7) * 8]);
        St[t] = __builtin_amdgcn_mfma_f32_32x32x16_bf16(kf, qf[0], z16, 0, 0, 0);
      }
#pragma unroll
      for (int s = 1; s < 4; s++) {
        int j8 = s * 2 + h;
        bf16x8 kf = *reinterpret_cast<const bf16x8*>(&Kc[row * 64 + ((j8 ^ row) & 7) * 8]);
        St[t] = __builtin_amdgcn_mfma_f32_32x32x16_bf16(kf, qf[s], St[t], 0, 0, 0);
      }
    }

    // max-free softmax: p = exp2(s), raw v_exp_f32 (s pre-scaled by log2e/8)
#pragma unroll
    for (int t = 0; t < 2; t++)
#pragma unroll
      for (int i = 0; i < 16; i++) {
        float p = __builtin_amdgcn_exp2f(St[t][i]);
        St[t][i] = p;
        l_i += p;
      }

    // PV: O^T(64x32) += V^T(64x64) P^T(64x32); P packs in-lane (sigma staging)
#pragma unroll
    for (int t = 0; t < 2; t++)
#pragma unroll
      for (int g = 0; g < 2; g++) {
        union { uint32 u[4]; bf16x8 v; } pb;
#pragma unroll
        for (int i = 0; i < 4; i++)
          pb.u[i] = pack_bf16x2(St[t][g * 8 + 2 * i], St[t][g * 8 + 2 * i + 1]);
        int j8 = t * 4 + g * 2 + h;   // key chunk along V's key axis
#pragma unroll
        for (int dt = 0; dt < 2; dt++) {
          int rowv = dt * 32 + l32;
          bf16x8 vf = *reinterpret_cast<const bf16x8*>(&Vc[rowv * 64 + ((j8 ^ rowv) & 7) * 8]);
          Ov[dt] = __builtin_amdgcn_mfma_f32_32x32x16_bf16(vf, pb.v, Ov[dt], 0, 0, 0);
        }
      }
  }

  // epilogue: unnormalized partial + l
  float l_tot = l_i + __shfl_xor(l_i, 32);
  int q = wq0 + l32;
  float* dstO = (half == 0 ? out : part + (size_t)(half - 1) * 4194304)
                + ((size_t)bb * 2048 + q) * 1024 + hh * 64;
#pragma unroll
  for (int dt = 0; dt < 2; dt++)
#pragma unroll
    for (int g = 0; g < 4; g++) {
      float4 o;
      o.x = Ov[dt][4 * g + 0];
      o.y = Ov[dt][4 * g + 1];
      o.z = Ov[dt][4 * g + 2];
      o.w = Ov[dt][4 * g + 3];
      *reinterpret_cast<float4*>(&dstO[dt * 32 + g * 8 + 4 * h]) = o;
    }
  if (h == 0) lbuf[half * 65536 + (bh << 11) + q] = l_tot;
}

// ---------------------------------------------------------------- combine
// out = (out + sum partials) / (sum l), elementwise float4.
__global__ __launch_bounds__(256) void combine_kernel(
    float* __restrict__ out, const float* __restrict__ part,
    const float* __restrict__ lbuf, int nsplit) {
  int i = blockIdx.x * 256 + threadIdx.x;   // float4 index, 1048576 total
  int e = i << 2;
  int brow = e >> 10;          // b*2048 + s
  int b = brow >> 11;
  int hcol = (e >> 6) & 15;
  int srow = brow & 2047;
  int lidx = ((b * 16 + hcol) << 11) + srow;
  float lsum = lbuf[lidx];
#pragma unroll 3
  for (int s = 1; s < nsplit; s++) lsum += lbuf[s * 65536 + lidx];
  float4 a = reinterpret_cast<const float4*>(out)[i];
#pragma unroll 3
  for (int s = 1; s < nsplit; s++) {
    float4 p = reinterpret_cast<const float4*>(part)[(size_t)(s - 1) * 1048576 + i];
    a.x += p.x; a.y += p.y; a.z += p.z; a.w += p.w;
  }
  float inv = 1.0f / lsum;
  a.x *= inv; a.y *= inv; a.z *= inv; a.w *= inv;
  reinterpret_cast<float4*>(out)[i] = a;
}

// ---------------------------------------------------------------- launch
extern "C" void kernel_launch(void* const* d_in, const int* in_sizes, int n_in,
                              void* d_out, int out_size, void* d_ws, size_t ws_size,
                              hipStream_t stream) {
  (void)in_sizes; (void)n_in; (void)out_size;
  const float* embed = (const float*)d_in[0];
  const float* qin   = (const float*)d_in[1];
  const float* Wk    = (const float*)d_in[2];
  const float* bk    = (const float*)d_in[3];
  const float* Wq    = (const float*)d_in[4];
  const float* bq    = (const float*)d_in[5];
  const float* Wv    = (const float*)d_in[6];
  const float* bv    = (const float*)d_in[7];
  float* out = (float*)d_out;

  // ws layout: [0, 23.07MB) bf16 cast buffers (consumed by proj);
  // [23.07, 48.23MB) Kp/Qp/Vt. Split-4 partials+l live after Vt (needs
  // ws >= 99,614,720 B); fallback split-2 reuses the dead cast region.
  bf16* ws = (bf16*)d_ws;
  bf16* emb_bf = ws;                       // 4,194,304 bf16
  bf16* q_bf   = emb_bf + 4194304;         // 4,194,304
  bf16* wk_bf  = q_bf   + 4194304;         // 1,048,576
  bf16* wq_bf  = wk_bf  + 1048576;
  bf16* wv_bf  = wq_bf  + 1048576;
  bf16* Kp     = wv_bf  + 1048576;         // [b,h,s,64]
  bf16* Qp     = Kp     + 4194304;         // [b,h,s,64], pre-scaled
  bf16* Vt     = Qp     + 4194304;         // [b,h,64,s]  (ends at byte 48,234,496)

  const bool big = (ws_size >= 99614720ull);
  const int lsplit = big ? 2 : 1;
  float* part, *lbuf;
  if (big) {
    part = (float*)((char*)d_ws + 48234496);   // 3 x 16,777,216 B fp32 partials
    lbuf = part + 3 * 4194304;                 // 4 x 65,536 fp32 l-sums
  } else {
    part = (float*)d_ws;                       // 1 partial in dead cast region
    lbuf = part + 4194304;                     // 2 x 65,536 l-sums
  }

  cast_all_kernel<<<11264, 256, 0, stream>>>(embed, qin, Wk, Wq, Wv, ws);

  proj_kernel<<<768, 256, 0, stream>>>(emb_bf, q_bf, wk_bf, wq_bf, wv_bf,
                                       bk, bq, bv, Kp, Qp, Vt);
  attn_kernel<<<512 << lsplit, 256, 0, stream>>>(Qp, Kp, Vt, out, part, lbuf, lsplit);
  combine_kernel<<<4096, 256, 0, stream>>>(out, part, lbuf, 1 << lsplit);
}

// Round 8
// 193.584 us; speedup vs baseline: 1.1754x; 1.1754x over previous
//
#include <hip/hip_runtime.h>
#include <cstdint>
#include <cstddef>

// CrossMultiheadAttention: B=2, S=2048, E=1024, NHEAD=16, HEAD=64
// cast fp32->bf16 (fused) -> MFMA QKV projection (Q pre-scaled by 0.125*log2e,
// V projection computes C^T so V^T stores coalesce) -> flash attention on
// mfma_f32_32x32x16_bf16, 64 queries/wave (each K/V LDS fragment feeds 2
// MFMAs), sigma-permuted K staging (P^T packs in-lane), max-free softmax
// (raw v_exp_f32), KV-split-2 -> combine normalizes.

using bf16 = __bf16;
typedef __bf16 bf16x8 __attribute__((ext_vector_type(8)));
typedef float f32x4 __attribute__((ext_vector_type(4)));
typedef float f32x16 __attribute__((ext_vector_type(16)));
using uint32 = unsigned int;

__device__ __forceinline__ void async16(void* lds, const void* g) {
  __builtin_amdgcn_global_load_lds((__attribute__((address_space(1))) void*)g,
                                   (__attribute__((address_space(3))) void*)lds,
                                   16, 0, 0);
}

__device__ __forceinline__ uint32 pack_bf16x2(float lo, float hi_) {
  union { bf16 h[2]; uint32 u; } w;
  w.h[0] = (bf16)lo; w.h[1] = (bf16)hi_;
  return w.u;
}

// ---------------------------------------------------------------- fused cast
// segments (float4 units): emb 1048576 | q 1048576 | wk 262144 | wq | wv
__global__ void cast_all_kernel(const float* __restrict__ e, const float* __restrict__ q,
                                const float* __restrict__ wk, const float* __restrict__ wq,
                                const float* __restrict__ wv, bf16* __restrict__ dst) {
  int i = blockIdx.x * blockDim.x + threadIdx.x;
  if (i >= 2883584) return;
  const float* src; int off;
  if (i < 1048576)      { src = e;  off = 0; }
  else if (i < 2097152) { src = q;  off = 1048576; }
  else if (i < 2359296) { src = wk; off = 2097152; }
  else if (i < 2621440) { src = wq; off = 2359296; }
  else                  { src = wv; off = 2621440; }
  float4 v = reinterpret_cast<const float4*>(src)[i - off];
  union { bf16 h[4]; unsigned long long u; } o;
  o.h[0] = (bf16)v.x; o.h[1] = (bf16)v.y; o.h[2] = (bf16)v.z; o.h[3] = (bf16)v.w;
  reinterpret_cast<unsigned long long*>(dst)[i] = o.u;
}

// ---------------------------------------------------------------- projection
// C[4096,1024] = A[4096,1024] @ W[1024,1024]^T (+bias). 128x128 tile, BK=64.
// proj 0: K -> Kp[b,h,s,64]; proj 1: Q*(0.125*log2e) -> Qp[b,h,s,64]
// proj 2: computes C^T (swapped MFMA operands) -> Vt[b,h,64,s], coalesced.
__global__ __launch_bounds__(256) void proj_kernel(
    const bf16* __restrict__ emb, const bf16* __restrict__ qin,
    const bf16* __restrict__ wk, const bf16* __restrict__ wq, const bf16* __restrict__ wv,
    const float* __restrict__ bk, const float* __restrict__ bq, const float* __restrict__ bv,
    bf16* __restrict__ Kp, bf16* __restrict__ Qp, bf16* __restrict__ Vt)
{
  __shared__ bf16 As[128 * 64];
  __shared__ bf16 Bs[128 * 64];

  int pid = blockIdx.x;
  int proj = pid >> 8;
  int t = pid & 255;
  int m0 = (t >> 3) * 128;
  int n0 = (t & 7) * 128;

  const bf16* A = (proj == 1) ? qin : emb;
  const bf16* W = (proj == 0) ? wk : (proj == 1) ? wq : wv;
  const float* bias = (proj == 0) ? bk : (proj == 1) ? bq : bv;
  const bool proj2 = (proj == 2);

  int tid = threadIdx.x;
  int lane = tid & 63, wid = tid >> 6;
  int quad = lane >> 4, l16 = lane & 15;
  int moff = (wid & 1) * 64, noff = (wid >> 1) * 64;

  f32x4 zero = {0.f, 0.f, 0.f, 0.f};
  f32x4 acc[4][4];
#pragma unroll
  for (int i = 0; i < 4; i++)
#pragma unroll
    for (int j = 0; j < 4; j++) acc[i][j] = zero;

  for (int kk = 0; kk < 1024; kk += 64) {
    __syncthreads();
#pragma unroll
    for (int i = 0; i < 4; i++) {
      int c = i * 256 + tid;
      int row = c >> 3;
      int ko = ((c ^ row) & 7) << 3;
      async16(&As[(size_t)(i * 256 + wid * 64) * 8], &A[(size_t)(m0 + row) * 1024 + kk + ko]);
      async16(&Bs[(size_t)(i * 256 + wid * 64) * 8], &W[(size_t)(n0 + row) * 1024 + kk + ko]);
    }
    __syncthreads();
#pragma unroll
    for (int ks = 0; ks < 2; ks++) {
      bf16x8 af[4], bfr[4];
#pragma unroll
      for (int i = 0; i < 4; i++) {
        int row = moff + i * 16 + l16;
        af[i] = *reinterpret_cast<const bf16x8*>(&As[row * 64 + ((((ks << 2) | quad) ^ row) & 7) * 8]);
      }
#pragma unroll
      for (int j = 0; j < 4; j++) {
        int row = noff + j * 16 + l16;
        bfr[j] = *reinterpret_cast<const bf16x8*>(&Bs[row * 64 + ((((ks << 2) | quad) ^ row) & 7) * 8]);
      }
      if (proj2) {
#pragma unroll
        for (int i = 0; i < 4; i++)
#pragma unroll
          for (int j = 0; j < 4; j++)
            acc[i][j] = __builtin_amdgcn_mfma_f32_16x16x32_bf16(bfr[j], af[i], acc[i][j], 0, 0, 0);
      } else {
#pragma unroll
        for (int i = 0; i < 4; i++)
#pragma unroll
          for (int j = 0; j < 4; j++)
            acc[i][j] = __builtin_amdgcn_mfma_f32_16x16x32_bf16(af[i], bfr[j], acc[i][j], 0, 0, 0);
      }
    }
  }

  if (proj2) {
#pragma unroll
    for (int i = 0; i < 4; i++) {
      int grow = m0 + moff + i * 16 + l16;
      int bb = grow >> 11;
      int ss = grow & 2047;
#pragma unroll
      for (int j = 0; j < 4; j++) {
#pragma unroll
        for (int r = 0; r < 4; r++) {
          int gcol = n0 + noff + j * 16 + quad * 4 + r;
          int hh = gcol >> 6, dd = gcol & 63;
          int bh = bb * 16 + hh;
          float v = acc[i][j][r] + bias[gcol];
          Vt[((size_t)bh * 64 + dd) * 2048 + ss] = (bf16)v;
        }
      }
    }
  } else {
    float bvv[4];
#pragma unroll
    for (int j = 0; j < 4; j++) bvv[j] = bias[n0 + noff + j * 16 + l16];
    bf16* dst = (proj == 0) ? Kp : Qp;
    // Q scale: 1/sqrt(64) * log2(e) so attention uses exp2 directly
    const float qs = (proj == 1) ? 0.18033688011112042f : 1.0f;
#pragma unroll
    for (int i = 0; i < 4; i++) {
#pragma unroll
      for (int r = 0; r < 4; r++) {
        int grow = m0 + moff + i * 16 + quad * 4 + r;
        int bb = grow >> 11;
        int ss = grow & 2047;
#pragma unroll
        for (int j = 0; j < 4; j++) {
          int gcol = n0 + noff + j * 16 + l16;
          int hh = gcol >> 6, dd = gcol & 63;
          int bh = bb * 16 + hh;
          float v = (acc[i][j][r] + bvv[j]) * qs;
          dst[((size_t)bh * 2048 + ss) * 64 + dd] = (bf16)v;
        }
      }
    }
  }
}

// ---------------------------------------------------------------- attention
// Grid 512: bid -> {half(1b), qblk(3b), bh(5b)}. Block = 4 waves; each wave
// owns 64 queries as two 32-query B-operand sets, so every K/V LDS fragment
// feeds two MFMAs (halves LDS read traffic per MFMA). sigma-permuted K staging
// (swap bits 2<->3 of row within each 16) makes S^T's C-layout rows already
// B-operand-ordered for PV: P^T packs in-lane. Max-free softmax: p = exp2(s)
// via raw v_exp_f32. Writes unnormalized O^T partial (fp32) + l; combine
// merges the two halves.
__global__ __launch_bounds__(256, 2) void attn_kernel(
    const bf16* __restrict__ Qp, const bf16* __restrict__ Kp, const bf16* __restrict__ Vt,
    float* __restrict__ out, float* __restrict__ part1, float* __restrict__ lbuf)
{
  __shared__ bf16 Ks[2][64 * 64];   // [key(sigma-permuted)][dim], chunk-swizzled
  __shared__ bf16 Vs[2][64 * 64];   // [dim][key], chunk-swizzled

  int bid = blockIdx.x;
  int half = bid & 1;
  int q0 = ((bid >> 1) & 7) << 8;   // 256-query block
  int bh = bid >> 4;
  int bb = bh >> 4, hh = bh & 15;
  int g0 = half << 4;               // first 64-key tile index

  const bf16* Qg = Qp + (size_t)bh * (2048 * 64);
  const bf16* Kg = Kp + (size_t)bh * (2048 * 64);
  const bf16* Vg = Vt + (size_t)bh * (64 * 2048);

  int tid = threadIdx.x, lane = tid & 63, wid = tid >> 6;
  int l32 = lane & 31;
  int h = lane >> 5;
  int wq0 = q0 + wid * 64;          // wave owns queries [wq0, wq0+64)

  auto stage = [&](int kt_, int buf) {   // kt_ = global 64-key tile index
#pragma unroll
    for (int i = 0; i < 2; i++) {
      int c = i * 256 + tid;
      int row = c >> 3;
      int srow = (row & ~12) | ((row & 4) << 1) | ((row & 8) >> 1);  // swap bits 2,3
      int ko = ((c ^ row) & 7) << 3;
      async16(&Ks[buf][(size_t)(i * 256 + wid * 64) * 8], &Kg[(size_t)(kt_ * 64 + srow) * 64 + ko]);
      async16(&Vs[buf][(size_t)(i * 256 + wid * 64) * 8], &Vg[(size_t)row * 2048 + kt_ * 64 + ko]);
    }
  };

  // Q^T B-operand fragments for both 32-query sets (b128 global, once)
  bf16x8 qf[2][4];
#pragma unroll
  for (int u = 0; u < 2; u++)
#pragma unroll
    for (int s = 0; s < 4; s++)
      qf[u][s] = *reinterpret_cast<const bf16x8*>(
          &Qg[(size_t)(wq0 + u * 32 + l32) * 64 + s * 16 + h * 8]);

  stage(g0, 0);

  const f32x16 z16 = {0.f, 0.f, 0.f, 0.f, 0.f, 0.f, 0.f, 0.f,
                      0.f, 0.f, 0.f, 0.f, 0.f, 0.f, 0.f, 0.f};
  f32x16 Ov[2][2];                  // [qset][dtile]
  Ov[0][0] = z16; Ov[0][1] = z16; Ov[1][0] = z16; Ov[1][1] = z16;
  float l_i[2] = {0.f, 0.f};

  for (int kt = 0; kt < 16; kt++) {
    int cur = kt & 1;
    __syncthreads();                          // staging for buf[cur] complete
    __builtin_amdgcn_sched_barrier(0);
    if (kt < 15) stage(g0 + kt + 1, cur ^ 1); // prefetch into other buffer
    __builtin_amdgcn_sched_barrier(0);

    const bf16* Kc = Ks[cur];
    const bf16* Vc = Vs[cur];

#pragma unroll
    for (int t = 0; t < 2; t++) {             // two 32-key tiles
      // S^T: each kf feeds both query sets
      f32x16 St[2];
      int row = t * 32 + l32;
      {
        bf16x8 kf = *reinterpret_cast<const bf16x8*>(&Kc[row * 64 + ((h ^ row) & 7) * 8]);
        St[0] = __builtin_amdgcn_mfma_f32_32x32x16_bf16(kf, qf[0][0], z16, 0, 0, 0);
        St[1] = __builtin_amdgcn_mfma_f32_32x32x16_bf16(kf, qf[1][0], z16, 0, 0, 0);
      }
#pragma unroll
      for (int s = 1; s < 4; s++) {
        int j8 = s * 2 + h;
        bf16x8 kf = *reinterpret_cast<const bf16x8*>(&Kc[row * 64 + ((j8 ^ row) & 7) * 8]);
        St[0] = __builtin_amdgcn_mfma_f32_32x32x16_bf16(kf, qf[0][s], St[0], 0, 0, 0);
        St[1] = __builtin_amdgcn_mfma_f32_32x32x16_bf16(kf, qf[1][s], St[1], 0, 0, 0);
      }

      // max-free softmax + in-lane bf16 pack (sigma staging ordered the keys)
      uint32 pk[2][8];
#pragma unroll
      for (int u = 0; u < 2; u++) {
#pragma unroll
        for (int i = 0; i < 16; i++) {
          float p = __builtin_amdgcn_exp2f(St[u][i]);
          St[u][i] = p;
          l_i[u] += p;
        }
#pragma unroll
        for (int i = 0; i < 8; i++)
          pk[u][i] = pack_bf16x2(St[u][2 * i], St[u][2 * i + 1]);
      }

      // PV: each vf feeds both query sets
#pragma unroll
      for (int g = 0; g < 2; g++) {
        union { uint32 u[4]; bf16x8 v; } pb0, pb1;
#pragma unroll
        for (int i = 0; i < 4; i++) { pb0.u[i] = pk[0][g * 4 + i]; pb1.u[i] = pk[1][g * 4 + i]; }
        int j8 = t * 4 + g * 2 + h;   // key chunk along V's key axis
#pragma unroll
        for (int dt = 0; dt < 2; dt++) {
          int rowv = dt * 32 + l32;
          bf16x8 vf = *reinterpret_cast<const bf16x8*>(&Vc[rowv * 64 + ((j8 ^ rowv) & 7) * 8]);
          Ov[0][dt] = __builtin_amdgcn_mfma_f32_32x32x16_bf16(vf, pb0.v, Ov[0][dt], 0, 0, 0);
          Ov[1][dt] = __builtin_amdgcn_mfma_f32_32x32x16_bf16(vf, pb1.v, Ov[1][dt], 0, 0, 0);
        }
      }
    }
  }

  // epilogue: unnormalized partials + l per query set
#pragma unroll
  for (int u = 0; u < 2; u++) {
    float l_tot = l_i[u] + __shfl_xor(l_i[u], 32);
    int q = wq0 + u * 32 + l32;
    float* dstO = (half == 0 ? out : part1) + ((size_t)bb * 2048 + q) * 1024 + hh * 64;
#pragma unroll
    for (int dt = 0; dt < 2; dt++)
#pragma unroll
      for (int g = 0; g < 4; g++) {
        float4 o;
        o.x = Ov[u][dt][4 * g + 0];
        o.y = Ov[u][dt][4 * g + 1];
        o.z = Ov[u][dt][4 * g + 2];
        o.w = Ov[u][dt][4 * g + 3];
        *reinterpret_cast<float4*>(&dstO[dt * 32 + g * 8 + 4 * h]) = o;
      }
    if (h == 0) lbuf[half * 65536 + (bh << 11) + q] = l_tot;
  }
}

// ---------------------------------------------------------------- combine
// out = (out + part1) / (l0 + l1), elementwise float4; l indexed per (bh, s).
__global__ __launch_bounds__(256) void combine_kernel(
    float* __restrict__ out, const float* __restrict__ part1,
    const float* __restrict__ lbuf) {
  int i = blockIdx.x * 256 + threadIdx.x;   // float4 index, 1048576 total
  int e = i << 2;
  int brow = e >> 10;          // b*2048 + s
  int b = brow >> 11;
  int hcol = (e >> 6) & 15;
  int srow = brow & 2047;
  int lidx = ((b * 16 + hcol) << 11) + srow;
  float inv = 1.0f / (lbuf[lidx] + lbuf[65536 + lidx]);
  float4 a = reinterpret_cast<const float4*>(out)[i];
  float4 p = reinterpret_cast<const float4*>(part1)[i];
  float4 r;
  r.x = (a.x + p.x) * inv;
  r.y = (a.y + p.y) * inv;
  r.z = (a.z + p.z) * inv;
  r.w = (a.w + p.w) * inv;
  reinterpret_cast<float4*>(out)[i] = r;
}

// ---------------------------------------------------------------- launch
extern "C" void kernel_launch(void* const* d_in, const int* in_sizes, int n_in,
                              void* d_out, int out_size, void* d_ws, size_t ws_size,
                              hipStream_t stream) {
  (void)in_sizes; (void)n_in; (void)out_size; (void)ws_size;
  const float* embed = (const float*)d_in[0];
  const float* qin   = (const float*)d_in[1];
  const float* Wk    = (const float*)d_in[2];
  const float* bk    = (const float*)d_in[3];
  const float* Wq    = (const float*)d_in[4];
  const float* bq    = (const float*)d_in[5];
  const float* Wv    = (const float*)d_in[6];
  const float* bv    = (const float*)d_in[7];
  float* out = (float*)d_out;

  // ws layout: [0, 23.07MB) bf16 cast buffers (consumed by proj); attn then
  // reuses the same bytes for the fp32 partial + l-sums.
  bf16* ws = (bf16*)d_ws;
  bf16* emb_bf = ws;                       // 4,194,304 bf16
  bf16* q_bf   = emb_bf + 4194304;         // 4,194,304
  bf16* wk_bf  = q_bf   + 4194304;         // 1,048,576
  bf16* wq_bf  = wk_bf  + 1048576;
  bf16* wv_bf  = wq_bf  + 1048576;
  bf16* Kp     = wv_bf  + 1048576;         // [b,h,s,64]
  bf16* Qp     = Kp     + 4194304;         // [b,h,s,64], pre-scaled
  bf16* Vt     = Qp     + 4194304;         // [b,h,64,s]

  float* part1 = (float*)d_ws;             // 4,194,304 f32 (dead cast region)
  float* lbuf  = part1 + 4194304;          // 2 x 65,536 f32

  cast_all_kernel<<<11264, 256, 0, stream>>>(embed, qin, Wk, Wq, Wv, ws);

  proj_kernel<<<768, 256, 0, stream>>>(emb_bf, q_bf, wk_bf, wq_bf, wv_bf,
                                       bk, bq, bv, Kp, Qp, Vt);
  attn_kernel<<<512, 256, 0, stream>>>(Qp, Kp, Vt, out, part1, lbuf);
  combine_kernel<<<4096, 256, 0, stream>>>(out, part1, lbuf);
}